// Round 5
// baseline (493.395 us; speedup 1.0000x reference)
//
#include <hip/hip_runtime.h>
#include <hip/hip_bf16.h>
#include <math.h>

typedef __bf16 bf16;
typedef __bf16 bf16x8 __attribute__((ext_vector_type(8)));
typedef float f32x4 __attribute__((ext_vector_type(4)));

__device__ __forceinline__ void gload_lds16(const bf16* g, bf16* l) {
  __builtin_amdgcn_global_load_lds(
      (const __attribute__((address_space(1))) void*)g,
      (__attribute__((address_space(3))) void*)l, 16, 0, 0);
}

// 256x256-tile GEMM, BK=64, 8 waves (2M x 4N), double-buffered LDS with
// stage-before-compute pipeline (T3/T4 minimum recipe) + chunk-XOR swizzle
// (T2, 0-conflict pattern proven in attn staging) + setprio (T5).
// C[M,N] = A[M,K] @ BT[N,K]^T, bf16 in, fp32 accum.
// EPI 0: out bf16 = acc + bias
// EPI 1: out f32  = acc + bias + res
// EPI 2: out bf16 = gelu_exact(acc + bias)
template <int EPI>
__global__ __launch_bounds__(512, 2)
void gemm256(const bf16* __restrict__ A, const bf16* __restrict__ BT,
             const float* __restrict__ bias, const float* __restrict__ res,
             void* __restrict__ Cout, int M, int N, int K)
{
  __shared__ alignas(16) bf16 lsA[2][256 * 64];
  __shared__ alignas(16) bf16 lsB[2][256 * 64];

  int nbn = N >> 8;
  int nwg = (M >> 8) * nbn;
  int bid = blockIdx.x;
  int cpx = nwg >> 3;                       // all grids divisible by 8
  int wg  = (bid & 7) * cpx + (bid >> 3);   // XCD-aware swizzle (bijective)
  int m0 = (wg / nbn) << 8;
  int n0 = (wg % nbn) << 8;

  int t  = threadIdx.x;
  int l  = t & 63;
  int w  = t >> 6;
  int wm = (w >> 2) << 7;   // 0 / 128
  int wn = (w & 3) << 6;    // 0 / 64 / 128 / 192
  int lr = l & 15;
  int lg = l >> 4;

  const bf16* Ag = A  + (size_t)m0 * K;
  const bf16* Bg = BT + (size_t)n0 * K;

  f32x4 acc[8][4];
  f32x4 zero = {0.f, 0.f, 0.f, 0.f};
#pragma unroll
  for (int mi = 0; mi < 8; ++mi)
#pragma unroll
    for (int ni = 0; ni < 4; ++ni) acc[mi][ni] = zero;

  int nk = K >> 6;
  // prologue: stage K-tile 0 -> buf 0 (pre-swizzled source, linear dest)
#pragma unroll
  for (int i = 0; i < 4; ++i) {
    int idx = i * 512 + t;
    int row = idx >> 3;
    int sch = ((idx & 7) ^ (row & 7)) << 3;
    gload_lds16(Ag + (size_t)row * K + sch, &lsA[0][idx << 3]);
    gload_lds16(Bg + (size_t)row * K + sch, &lsB[0][idx << 3]);
  }
  __syncthreads();

  int cur = 0;
  for (int kt = 0; kt < nk; ++kt) {
    // issue next tile's staging FIRST; its vmcnt drain happens at the
    // end-of-iteration barrier, ~64 MFMAs later (latency hidden)
    if (kt + 1 < nk) {
      int k0n = (kt + 1) << 6;
#pragma unroll
      for (int i = 0; i < 4; ++i) {
        int idx = i * 512 + t;
        int row = idx >> 3;
        int sch = ((idx & 7) ^ (row & 7)) << 3;
        gload_lds16(Ag + (size_t)row * K + k0n + sch, &lsA[cur ^ 1][idx << 3]);
        gload_lds16(Bg + (size_t)row * K + k0n + sch, &lsB[cur ^ 1][idx << 3]);
      }
    }
    // B fragments once per K-tile (shared by all 4 quadrant phases)
    bf16x8 bfr[4][2];
#pragma unroll
    for (int ni = 0; ni < 4; ++ni)
#pragma unroll
      for (int kk = 0; kk < 2; ++kk) {
        int brow = wn + ni * 16 + lr;
        bfr[ni][kk] = *(const bf16x8*)&lsB[cur][brow * 64 + (((kk * 4 + lg) ^ (brow & 7)) << 3)];
      }
    // 4 quadrant phases: {ds_read A-quad, 16 MFMA}
#pragma unroll
    for (int qd = 0; qd < 4; ++qd) {
      bf16x8 af[2][2];
#pragma unroll
      for (int mi = 0; mi < 2; ++mi)
#pragma unroll
        for (int kk = 0; kk < 2; ++kk) {
          int arow = wm + (qd * 2 + mi) * 16 + lr;
          af[mi][kk] = *(const bf16x8*)&lsA[cur][arow * 64 + (((kk * 4 + lg) ^ (arow & 7)) << 3)];
        }
      __builtin_amdgcn_s_setprio(1);
#pragma unroll
      for (int mi = 0; mi < 2; ++mi)
#pragma unroll
        for (int ni = 0; ni < 4; ++ni)
#pragma unroll
          for (int kk = 0; kk < 2; ++kk)
            acc[qd * 2 + mi][ni] = __builtin_amdgcn_mfma_f32_16x16x32_bf16(
                af[mi][kk], bfr[ni][kk], acc[qd * 2 + mi][ni], 0, 0, 0);
      __builtin_amdgcn_s_setprio(0);
    }
    __syncthreads();
    cur ^= 1;
  }

  // epilogue
#pragma unroll
  for (int mi = 0; mi < 8; ++mi) {
    int row = m0 + wm + mi * 16 + lg * 4;
#pragma unroll
    for (int ni = 0; ni < 4; ++ni) {
      int col = n0 + wn + ni * 16 + lr;
      float bv = bias[col];
      f32x4 a = acc[mi][ni];
#pragma unroll
      for (int r = 0; r < 4; ++r) {
        float v = a[r] + bv;
        size_t idx = (size_t)(row + r) * N + col;
        if (EPI == 0) {
          ((bf16*)Cout)[idx] = (bf16)v;
        } else if (EPI == 1) {
          ((float*)Cout)[idx] = v + res[idx];
        } else {
          v = 0.5f * v * (1.f + erff(v * 0.70710678118654752f));
          ((bf16*)Cout)[idx] = (bf16)v;
        }
      }
    }
  }
}

// LayerNorm over last dim (1024), fp32 in -> bf16 out. One block per row.
__global__ __launch_bounds__(256)
void ln_bf16(const float* __restrict__ x, const float* __restrict__ w,
             const float* __restrict__ b, bf16* __restrict__ out)
{
  int row = blockIdx.x;
  int t = threadIdx.x;
  float4 v = ((const float4*)(x + (size_t)row * 1024))[t];
  float s  = v.x + v.y + v.z + v.w;
  float sq = v.x * v.x + v.y * v.y + v.z * v.z + v.w * v.w;
#pragma unroll
  for (int off = 32; off >= 1; off >>= 1) {
    s  += __shfl_xor(s, off);
    sq += __shfl_xor(sq, off);
  }
  __shared__ float ps[4], pq[4];
  if ((t & 63) == 0) { ps[t >> 6] = s; pq[t >> 6] = sq; }
  __syncthreads();
  s  = ps[0] + ps[1] + ps[2] + ps[3];
  sq = pq[0] + pq[1] + pq[2] + pq[3];
  float mu  = s * (1.f / 1024.f);
  float var = sq * (1.f / 1024.f) - mu * mu;
  float rstd = rsqrtf(var + 1e-5f);
  float4 wv = ((const float4*)w)[t];
  float4 bv = ((const float4*)b)[t];
  size_t o0 = (size_t)row * 1024 + t * 4;
  out[o0 + 0] = (bf16)((v.x - mu) * rstd * wv.x + bv.x);
  out[o0 + 1] = (bf16)((v.y - mu) * rstd * wv.y + bv.y);
  out[o0 + 2] = (bf16)((v.z - mu) * rstd * wv.z + bv.z);
  out[o0 + 3] = (bf16)((v.w - mu) * rstd * wv.w + bv.w);
}

// WT[N,K] (bf16) = W[K,N] (f32) transposed+cast. grid=(K/32, N/32), 256 thr.
__global__ __launch_bounds__(256)
void transpose_cast(const float* __restrict__ W, bf16* __restrict__ WT, int K, int N)
{
  __shared__ float tile[32][33];
  int bk = blockIdx.x * 32, bn = blockIdx.y * 32;
  int tx = threadIdx.x & 31, ty = threadIdx.x >> 5;
#pragma unroll
  for (int i = ty; i < 32; i += 8)
    tile[i][tx] = W[(size_t)(bk + i) * N + bn + tx];
  __syncthreads();
#pragma unroll
  for (int i = ty; i < 32; i += 8)
    WT[(size_t)(bn + i) * K + bk + tx] = (bf16)tile[tx][i];
}

// V transpose: vt[(b*16+h)*64 + d][t] = qkv[(b*2048+t)*3072 + 2048 + h*64 + d]
// 64 tokens x 64 dims per block; XOR-swizzled LDS chunks. grid=(64, 32).
__global__ __launch_bounds__(256)
void vtrans(const bf16* __restrict__ qkv, bf16* __restrict__ vt)
{
  __shared__ alignas(16) bf16 tile[64 * 64];
  int bh = blockIdx.x;
  int b = bh >> 4, h = bh & 15;
  int t0 = blockIdx.y * 64;
  int t = threadIdx.x;
#pragma unroll
  for (int i = 0; i < 2; ++i) {
    int c = i * 256 + t;
    int tt = c >> 3, d8 = c & 7;
    bf16x8 v = *(const bf16x8*)(qkv + (size_t)(b * 2048 + t0 + tt) * 3072 + 2048 + h * 64 + d8 * 8);
    *(bf16x8*)&tile[(tt * 8 + (d8 ^ (tt >> 3))) * 8] = v;
  }
  __syncthreads();
#pragma unroll
  for (int i = 0; i < 2; ++i) {
    int c = i * 256 + t;
    int d = c >> 3, tt8 = c & 7;
    bf16x8 o;
#pragma unroll
    for (int j = 0; j < 8; ++j) {
      int row = tt8 * 8 + j;
      o[j] = tile[(row * 8 + ((d >> 3) ^ (row >> 3))) * 8 + (d & 7)];
    }
    *(bf16x8*)(vt + (size_t)(bh * 64 + d) * 2048 + t0 + tt8 * 8) = o;
  }
}

// Flash causal attention, block-cooperative + fixed-cap softmax.
// Block = 4 waves = 64 q-rows of one head; KVBLK=64; K/V^T staged to LDS
// (XOR-swizzled via pre-swizzled global_load_lds source). Big-q first.
__global__ __launch_bounds__(256)
void attn_flash(const bf16* __restrict__ qkv, const bf16* __restrict__ vt,
                bf16* __restrict__ y)
{
  __shared__ alignas(16) bf16 lk[64 * 64];
  __shared__ alignas(16) bf16 lv[64 * 64];
  __shared__ alignas(16) bf16 lp[4][16 * 64];

  int bid = blockIdx.x;
  int bh = bid & 63;
  int qb = 31 - (bid >> 6);
  int b = bh >> 4, h = bh & 15;
  int t = threadIdx.x;
  int w = t >> 6, l = t & 63;
  int lr = l & 15, lg = l >> 4;
  int q0 = qb * 64;
  int qw = q0 + w * 16;
  const size_t RS = 3072;
  const float SCL = 0.18033688011112042f;   // 0.125 * log2(e)

  const bf16* qbase = qkv + (size_t)(b * 2048) * RS + h * 64;
  const bf16* kbase = qkv + (size_t)(b * 2048) * RS + 1024 + h * 64;
  const bf16* vtb   = vt + (size_t)(bh * 64) * 2048;

  bf16x8 qf[2];
#pragma unroll
  for (int kk = 0; kk < 2; ++kk)
    qf[kk] = *(const bf16x8*)(qbase + (size_t)(qw + lr) * RS + kk * 32 + lg * 8);

  f32x4 zero = {0.f, 0.f, 0.f, 0.f};
  f32x4 o[4];
#pragma unroll
  for (int ni = 0; ni < 4; ++ni) o[ni] = zero;
  float lo[4] = {0.f, 0.f, 0.f, 0.f};

  int nkb = qb + 1;
  for (int kb = 0; kb < nkb; ++kb) {
    int k0 = kb * 64;
#pragma unroll
    for (int i = 0; i < 2; ++i) {
      int c = i * 256 + t;
      int row = c >> 3, c8 = c & 7;
      int sc8 = c8 ^ (row & 7);
      gload_lds16(kbase + (size_t)(k0 + row) * RS + sc8 * 8, &lk[c * 8]);
      gload_lds16(vtb + (size_t)row * 2048 + k0 + sc8 * 8, &lv[c * 8]);
    }
    __syncthreads();

    f32x4 s[4];
#pragma unroll
    for (int j = 0; j < 4; ++j) s[j] = zero;
#pragma unroll
    for (int kk = 0; kk < 2; ++kk)
#pragma unroll
      for (int j = 0; j < 4; ++j) {
        int krow = j * 16 + lr;
        bf16x8 kf = *(const bf16x8*)&lk[krow * 64 + (((4 * kk + lg) ^ (krow & 7)) * 8)];
        s[j] = __builtin_amdgcn_mfma_f32_16x16x32_bf16(qf[kk], kf, s[j], 0, 0, 0);
      }

    bool needmask = (kb == qb);
    float p[4][4];
#pragma unroll
    for (int r = 0; r < 4; ++r) {
      int tq = qw + lg * 4 + r;
#pragma unroll
      for (int j = 0; j < 4; ++j) {
        float v = s[j][r] * SCL;
        if (needmask && (k0 + j * 16 + lr > tq)) v = -1e30f;
        p[j][r] = exp2f(v);
      }
      lo[r] += (p[0][r] + p[1][r]) + (p[2][r] + p[3][r]);
    }

#pragma unroll
    for (int r = 0; r < 4; ++r) {
      int qr = lg * 4 + r;
#pragma unroll
      for (int j = 0; j < 4; ++j) {
        int ch = (2 * j + (lr >> 3)) ^ (qr & 7);
        lp[w][qr * 64 + ch * 8 + (lr & 7)] = (bf16)p[j][r];
      }
    }
    bf16x8 pa[2];
#pragma unroll
    for (int kf = 0; kf < 2; ++kf)
      pa[kf] = *(const bf16x8*)&lp[w][lr * 64 + (((4 * kf + lg) ^ (lr & 7)) * 8)];

#pragma unroll
    for (int ni = 0; ni < 4; ++ni)
#pragma unroll
      for (int kf = 0; kf < 2; ++kf) {
        int d = ni * 16 + lr;
        bf16x8 vf = *(const bf16x8*)&lv[d * 64 + (((4 * kf + lg) ^ (d & 7)) * 8)];
        o[ni] = __builtin_amdgcn_mfma_f32_16x16x32_bf16(pa[kf], vf, o[ni], 0, 0, 0);
      }
    __syncthreads();
  }

#pragma unroll
  for (int r = 0; r < 4; ++r) {
#pragma unroll
    for (int off = 1; off < 16; off <<= 1) lo[r] += __shfl_xor(lo[r], off);
    lo[r] = 1.f / lo[r];
  }
#pragma unroll
  for (int ni = 0; ni < 4; ++ni)
#pragma unroll
    for (int r = 0; r < 4; ++r) {
      int tq = qw + lg * 4 + r;
      y[(size_t)(b * 2048 + tq) * 1024 + h * 64 + ni * 16 + lr] = (bf16)(o[ni][r] * lo[r]);
    }
}

extern "C" void kernel_launch(void* const* d_in, const int* in_sizes, int n_in,
                              void* d_out, int out_size, void* d_ws, size_t ws_size,
                              hipStream_t stream) {
  (void)in_sizes; (void)n_in; (void)out_size; (void)ws_size;
  const float* x      = (const float*)d_in[0];
  const float* ln1w   = (const float*)d_in[1];
  const float* ln1b   = (const float*)d_in[2];
  const float* ln2w   = (const float*)d_in[3];
  const float* ln2b   = (const float*)d_in[4];
  const float* w_attn = (const float*)d_in[5];
  const float* b_attn = (const float*)d_in[6];
  const float* w_proj = (const float*)d_in[7];
  const float* b_proj = (const float*)d_in[8];
  const float* w_fc   = (const float*)d_in[9];
  const float* b_fc   = (const float*)d_in[10];
  const float* w_fc2  = (const float*)d_in[11];
  const float* b_fc2  = (const float*)d_in[12];
  float* out = (float*)d_out;

  // workspace layout: h | [qkv | y] == m | x1 (vt overlays x1) | weightsT
  char* p = (char*)d_ws;
  bf16*  h     = (bf16*)p;  p += (size_t)8192 * 1024 * 2;
  bf16*  qkv   = (bf16*)p;
  bf16*  mbuf  = (bf16*)p;  p += (size_t)8192 * 3072 * 2;   // m overlays qkv+y
  bf16*  ybuf  = (bf16*)p;  p += (size_t)8192 * 1024 * 2;
  float* x1    = (float*)p; p += (size_t)8192 * 1024 * 4;
  bf16*  wqkvT = (bf16*)p;  p += (size_t)3072 * 1024 * 2;
  bf16*  wprojT= (bf16*)p;  p += (size_t)1024 * 1024 * 2;
  bf16*  wfcT  = (bf16*)p;  p += (size_t)4096 * 1024 * 2;
  bf16*  wfc2T = (bf16*)p;  p += (size_t)1024 * 4096 * 2;
  bf16*  vt    = (bf16*)x1;   // dead until proj-GEMM writes x1 (after attn)

  transpose_cast<<<dim3(1024 / 32, 3072 / 32), 256, 0, stream>>>(w_attn, wqkvT, 1024, 3072);
  transpose_cast<<<dim3(1024 / 32, 1024 / 32), 256, 0, stream>>>(w_proj, wprojT, 1024, 1024);
  transpose_cast<<<dim3(1024 / 32, 4096 / 32), 256, 0, stream>>>(w_fc,   wfcT,  1024, 4096);
  transpose_cast<<<dim3(4096 / 32, 1024 / 32), 256, 0, stream>>>(w_fc2,  wfc2T, 4096, 1024);

  ln_bf16<<<8192, 256, 0, stream>>>(x, ln1w, ln1b, h);
  gemm256<0><<<384, 512, 0, stream>>>(h, wqkvT, b_attn, nullptr, qkv, 8192, 3072, 1024);
  vtrans<<<dim3(64, 32), 256, 0, stream>>>(qkv, vt);
  attn_flash<<<2048, 256, 0, stream>>>(qkv, vt, ybuf);
  gemm256<1><<<128, 512, 0, stream>>>(ybuf, wprojT, b_proj, x, x1, 8192, 1024, 1024);
  ln_bf16<<<8192, 256, 0, stream>>>(x1, ln2w, ln2b, h);
  gemm256<2><<<512, 512, 0, stream>>>(h, wfcT, b_fc, nullptr, mbuf, 8192, 4096, 1024);
  gemm256<1><<<128, 512, 0, stream>>>(mbuf, wfc2T, b_fc2, x1, out, 8192, 1024, 4096);
}

// Round 6
// 445.866 us; speedup vs baseline: 1.1066x; 1.1066x over previous
//
#include <hip/hip_runtime.h>
#include <hip/hip_bf16.h>
#include <math.h>

typedef __bf16 bf16;
typedef __bf16 bf16x8 __attribute__((ext_vector_type(8)));
typedef float f32x4 __attribute__((ext_vector_type(4)));

__device__ __forceinline__ void gload_lds16(const bf16* g, bf16* l) {
  __builtin_amdgcn_global_load_lds(
      (const __attribute__((address_space(1))) void*)g,
      (__attribute__((address_space(3))) void*)l, 16, 0, 0);
}

// 256x128-tile GEMM, BK=64, TRIPLE-buffered LDS (stage 2 K-tiles ahead,
// counted vmcnt(6) at tile boundaries -- no vmcnt(0) drain in steady loop),
// 8 waves (4M x 2N, 64x64 out per wave), 2 phases/tile with barrier-pair
// rhythm + setprio (T3/T4/T5), chunk-XOR LDS swizzle (T2, proven 0-conflict).
// C[M,N] = A[M,K] @ BT[N,K]^T, bf16 in, fp32 accum.
// EPI 0: out bf16 = acc + bias
// EPI 1: out f32  = acc + bias + res
// EPI 2: out bf16 = gelu_exact(acc + bias)
template <int EPI>
__global__ __launch_bounds__(512, 2)
void gemm3(const bf16* __restrict__ A, const bf16* __restrict__ BT,
           const float* __restrict__ bias, const float* __restrict__ res,
           void* __restrict__ Cout, int M, int N, int K)
{
  __shared__ alignas(16) bf16 lsA[3][256 * 64];   // 96 KB
  __shared__ alignas(16) bf16 lsB[3][128 * 64];   // 48 KB

  int nbn = N >> 7;
  int nwg = (M >> 8) * nbn;
  int bid = blockIdx.x;
  int cpx = nwg >> 3;                       // all grids divisible by 8
  int wg  = (bid & 7) * cpx + (bid >> 3);   // XCD-aware swizzle (bijective)
  int m0 = (wg / nbn) << 8;
  int n0 = (wg % nbn) << 7;

  int t  = threadIdx.x;
  int l  = t & 63;
  int w  = t >> 6;
  int wm = (w >> 1) << 6;   // 0/64/128/192
  int wn = (w & 1) << 6;    // 0/64
  int lr = l & 15;
  int lg = l >> 4;

  const bf16* Ag = A  + (size_t)m0 * K;
  const bf16* Bg = BT + (size_t)n0 * K;

  f32x4 acc[4][4];
  f32x4 zero = {0.f, 0.f, 0.f, 0.f};
#pragma unroll
  for (int mi = 0; mi < 4; ++mi)
#pragma unroll
    for (int ni = 0; ni < 4; ++ni) acc[mi][ni] = zero;

  int nt = K >> 6;

  // ---- prologue: stage tiles 0 and 1 (6 loads each) ----
#pragma unroll
  for (int pt = 0; pt < 2; ++pt) {
#pragma unroll
    for (int r = 0; r < 4; ++r) {
      int idx = r * 512 + t;
      int row = idx >> 3;
      gload_lds16(Ag + (size_t)row * K + pt * 64 + (((idx & 7) ^ (row & 7)) << 3),
                  &lsA[pt][idx << 3]);
    }
#pragma unroll
    for (int r = 0; r < 2; ++r) {
      int idx = r * 512 + t;
      int row = idx >> 3;
      gload_lds16(Bg + (size_t)row * K + pt * 64 + (((idx & 7) ^ (row & 7)) << 3),
                  &lsB[pt][idx << 3]);
    }
  }
  asm volatile("s_waitcnt vmcnt(6)" ::: "memory");  // tile0 complete; tile1 in flight
  __builtin_amdgcn_s_barrier();

  int cb = 0, sb = 2;
  for (int T = 0; T < nt; ++T) {
    const bf16* bufA = &lsA[cb][0];
    const bf16* bufB = &lsB[cb][0];
    bf16* stA = &lsA[sb][0];
    bf16* stB = &lsB[sb][0];
    bool doStage = (T + 2 < nt);
    int k0s = (T + 2) << 6;

    // ================ phase 0 ================
    bf16x8 bfr[4][2];
#pragma unroll
    for (int ni = 0; ni < 4; ++ni)
#pragma unroll
      for (int kk = 0; kk < 2; ++kk) {
        int brow = wn + ni * 16 + lr;
        bfr[ni][kk] = *(const bf16x8*)&bufB[brow * 64 + (((kk * 4 + lg) ^ (brow & 7)) << 3)];
      }
    bf16x8 af0[2][2];
#pragma unroll
    for (int mi = 0; mi < 2; ++mi)
#pragma unroll
      for (int kk = 0; kk < 2; ++kk) {
        int arow = wm + mi * 16 + lr;
        af0[mi][kk] = *(const bf16x8*)&bufA[arow * 64 + (((kk * 4 + lg) ^ (arow & 7)) << 3)];
      }
    if (doStage) {
#pragma unroll
      for (int r = 0; r < 3; ++r) {       // A rows 0..191 of tile T+2
        int idx = r * 512 + t;
        int row = idx >> 3;
        gload_lds16(Ag + (size_t)row * K + k0s + (((idx & 7) ^ (row & 7)) << 3),
                    &stA[idx << 3]);
      }
    }
    __builtin_amdgcn_s_barrier();
    asm volatile("s_waitcnt lgkmcnt(0)" ::: "memory");
    __builtin_amdgcn_s_setprio(1);
#pragma unroll
    for (int mi = 0; mi < 2; ++mi)
#pragma unroll
      for (int ni = 0; ni < 4; ++ni)
#pragma unroll
        for (int kk = 0; kk < 2; ++kk)
          acc[mi][ni] = __builtin_amdgcn_mfma_f32_16x16x32_bf16(
              af0[mi][kk], bfr[ni][kk], acc[mi][ni], 0, 0, 0);
    __builtin_amdgcn_s_setprio(0);
    __builtin_amdgcn_s_barrier();

    // ================ phase 1 ================
    bf16x8 af1[2][2];
#pragma unroll
    for (int mi = 0; mi < 2; ++mi)
#pragma unroll
      for (int kk = 0; kk < 2; ++kk) {
        int arow = wm + (mi + 2) * 16 + lr;
        af1[mi][kk] = *(const bf16x8*)&bufA[arow * 64 + (((kk * 4 + lg) ^ (arow & 7)) << 3)];
      }
    if (doStage) {
      {                                   // A rows 192..255 of tile T+2
        int idx = 3 * 512 + t;
        int row = idx >> 3;
        gload_lds16(Ag + (size_t)row * K + k0s + (((idx & 7) ^ (row & 7)) << 3),
                    &stA[idx << 3]);
      }
#pragma unroll
      for (int r = 0; r < 2; ++r) {       // B rows 0..127 of tile T+2
        int idx = r * 512 + t;
        int row = idx >> 3;
        gload_lds16(Bg + (size_t)row * K + k0s + (((idx & 7) ^ (row & 7)) << 3),
                    &stB[idx << 3]);
      }
    }
    __builtin_amdgcn_s_barrier();
    asm volatile("s_waitcnt lgkmcnt(0)" ::: "memory");
    __builtin_amdgcn_s_setprio(1);
#pragma unroll
    for (int mi = 0; mi < 2; ++mi)
#pragma unroll
      for (int ni = 0; ni < 4; ++ni)
#pragma unroll
        for (int kk = 0; kk < 2; ++kk)
          acc[mi + 2][ni] = __builtin_amdgcn_mfma_f32_16x16x32_bf16(
              af1[mi][kk], bfr[ni][kk], acc[mi + 2][ni], 0, 0, 0);
    __builtin_amdgcn_s_setprio(0);
    // boundary wait BEFORE barrier: after barrier, ALL waves' loads for
    // tile T+1 are counted-complete (vmcnt retires oldest-first).
    if (doStage) asm volatile("s_waitcnt vmcnt(6)" ::: "memory");
    else         asm volatile("s_waitcnt vmcnt(0)" ::: "memory");
    __builtin_amdgcn_s_barrier();

    cb = (cb == 2) ? 0 : cb + 1;
    sb = (sb == 2) ? 0 : sb + 1;
  }

  // epilogue
#pragma unroll
  for (int mi = 0; mi < 4; ++mi) {
    int row = m0 + wm + mi * 16 + lg * 4;
#pragma unroll
    for (int ni = 0; ni < 4; ++ni) {
      int col = n0 + wn + ni * 16 + lr;
      float bv = bias[col];
      f32x4 a = acc[mi][ni];
#pragma unroll
      for (int r = 0; r < 4; ++r) {
        float v = a[r] + bv;
        size_t idx = (size_t)(row + r) * N + col;
        if (EPI == 0) {
          ((bf16*)Cout)[idx] = (bf16)v;
        } else if (EPI == 1) {
          ((float*)Cout)[idx] = v + res[idx];
        } else {
          v = 0.5f * v * (1.f + erff(v * 0.70710678118654752f));
          ((bf16*)Cout)[idx] = (bf16)v;
        }
      }
    }
  }
}

// LayerNorm over last dim (1024), fp32 in -> bf16 out. One block per row.
__global__ __launch_bounds__(256)
void ln_bf16(const float* __restrict__ x, const float* __restrict__ w,
             const float* __restrict__ b, bf16* __restrict__ out)
{
  int row = blockIdx.x;
  int t = threadIdx.x;
  float4 v = ((const float4*)(x + (size_t)row * 1024))[t];
  float s  = v.x + v.y + v.z + v.w;
  float sq = v.x * v.x + v.y * v.y + v.z * v.z + v.w * v.w;
#pragma unroll
  for (int off = 32; off >= 1; off >>= 1) {
    s  += __shfl_xor(s, off);
    sq += __shfl_xor(sq, off);
  }
  __shared__ float ps[4], pq[4];
  if ((t & 63) == 0) { ps[t >> 6] = s; pq[t >> 6] = sq; }
  __syncthreads();
  s  = ps[0] + ps[1] + ps[2] + ps[3];
  sq = pq[0] + pq[1] + pq[2] + pq[3];
  float mu  = s * (1.f / 1024.f);
  float var = sq * (1.f / 1024.f) - mu * mu;
  float rstd = rsqrtf(var + 1e-5f);
  float4 wv = ((const float4*)w)[t];
  float4 bv = ((const float4*)b)[t];
  size_t o0 = (size_t)row * 1024 + t * 4;
  out[o0 + 0] = (bf16)((v.x - mu) * rstd * wv.x + bv.x);
  out[o0 + 1] = (bf16)((v.y - mu) * rstd * wv.y + bv.y);
  out[o0 + 2] = (bf16)((v.z - mu) * rstd * wv.z + bv.z);
  out[o0 + 3] = (bf16)((v.w - mu) * rstd * wv.w + bv.w);
}

// WT[N,K] (bf16) = W[K,N] (f32) transposed+cast. grid=(K/32, N/32), 256 thr.
__global__ __launch_bounds__(256)
void transpose_cast(const float* __restrict__ W, bf16* __restrict__ WT, int K, int N)
{
  __shared__ float tile[32][33];
  int bk = blockIdx.x * 32, bn = blockIdx.y * 32;
  int tx = threadIdx.x & 31, ty = threadIdx.x >> 5;
#pragma unroll
  for (int i = ty; i < 32; i += 8)
    tile[i][tx] = W[(size_t)(bk + i) * N + bn + tx];
  __syncthreads();
#pragma unroll
  for (int i = ty; i < 32; i += 8)
    WT[(size_t)(bn + i) * K + bk + tx] = (bf16)tile[tx][i];
}

// V transpose: vt[(b*16+h)*64 + d][t] = qkv[(b*2048+t)*3072 + 2048 + h*64 + d]
__global__ __launch_bounds__(256)
void vtrans(const bf16* __restrict__ qkv, bf16* __restrict__ vt)
{
  __shared__ alignas(16) bf16 tile[64 * 64];
  int bh = blockIdx.x;
  int b = bh >> 4, h = bh & 15;
  int t0 = blockIdx.y * 64;
  int t = threadIdx.x;
#pragma unroll
  for (int i = 0; i < 2; ++i) {
    int c = i * 256 + t;
    int tt = c >> 3, d8 = c & 7;
    bf16x8 v = *(const bf16x8*)(qkv + (size_t)(b * 2048 + t0 + tt) * 3072 + 2048 + h * 64 + d8 * 8);
    *(bf16x8*)&tile[(tt * 8 + (d8 ^ (tt >> 3))) * 8] = v;
  }
  __syncthreads();
#pragma unroll
  for (int i = 0; i < 2; ++i) {
    int c = i * 256 + t;
    int d = c >> 3, tt8 = c & 7;
    bf16x8 o;
#pragma unroll
    for (int j = 0; j < 8; ++j) {
      int row = tt8 * 8 + j;
      o[j] = tile[(row * 8 + ((d >> 3) ^ (row >> 3))) * 8 + (d & 7)];
    }
    *(bf16x8*)(vt + (size_t)(bh * 64 + d) * 2048 + t0 + tt8 * 8) = o;
  }
}

// Flash causal attention, block-cooperative + fixed-cap softmax.
__global__ __launch_bounds__(256)
void attn_flash(const bf16* __restrict__ qkv, const bf16* __restrict__ vt,
                bf16* __restrict__ y)
{
  __shared__ alignas(16) bf16 lk[64 * 64];
  __shared__ alignas(16) bf16 lv[64 * 64];
  __shared__ alignas(16) bf16 lp[4][16 * 64];

  int bid = blockIdx.x;
  int bh = bid & 63;
  int qb = 31 - (bid >> 6);
  int b = bh >> 4, h = bh & 15;
  int t = threadIdx.x;
  int w = t >> 6, l = t & 63;
  int lr = l & 15, lg = l >> 4;
  int q0 = qb * 64;
  int qw = q0 + w * 16;
  const size_t RS = 3072;
  const float SCL = 0.18033688011112042f;   // 0.125 * log2(e)

  const bf16* qbase = qkv + (size_t)(b * 2048) * RS + h * 64;
  const bf16* kbase = qkv + (size_t)(b * 2048) * RS + 1024 + h * 64;
  const bf16* vtb   = vt + (size_t)(bh * 64) * 2048;

  bf16x8 qf[2];
#pragma unroll
  for (int kk = 0; kk < 2; ++kk)
    qf[kk] = *(const bf16x8*)(qbase + (size_t)(qw + lr) * RS + kk * 32 + lg * 8);

  f32x4 zero = {0.f, 0.f, 0.f, 0.f};
  f32x4 o[4];
#pragma unroll
  for (int ni = 0; ni < 4; ++ni) o[ni] = zero;
  float lo[4] = {0.f, 0.f, 0.f, 0.f};

  int nkb = qb + 1;
  for (int kb = 0; kb < nkb; ++kb) {
    int k0 = kb * 64;
#pragma unroll
    for (int i = 0; i < 2; ++i) {
      int c = i * 256 + t;
      int row = c >> 3, c8 = c & 7;
      int sc8 = c8 ^ (row & 7);
      gload_lds16(kbase + (size_t)(k0 + row) * RS + sc8 * 8, &lk[c * 8]);
      gload_lds16(vtb + (size_t)row * 2048 + k0 + sc8 * 8, &lv[c * 8]);
    }
    __syncthreads();

    f32x4 s[4];
#pragma unroll
    for (int j = 0; j < 4; ++j) s[j] = zero;
#pragma unroll
    for (int kk = 0; kk < 2; ++kk)
#pragma unroll
      for (int j = 0; j < 4; ++j) {
        int krow = j * 16 + lr;
        bf16x8 kf = *(const bf16x8*)&lk[krow * 64 + (((4 * kk + lg) ^ (krow & 7)) * 8)];
        s[j] = __builtin_amdgcn_mfma_f32_16x16x32_bf16(qf[kk], kf, s[j], 0, 0, 0);
      }

    bool needmask = (kb == qb);
    float p[4][4];
#pragma unroll
    for (int r = 0; r < 4; ++r) {
      int tq = qw + lg * 4 + r;
#pragma unroll
      for (int j = 0; j < 4; ++j) {
        float v = s[j][r] * SCL;
        if (needmask && (k0 + j * 16 + lr > tq)) v = -1e30f;
        p[j][r] = exp2f(v);
      }
      lo[r] += (p[0][r] + p[1][r]) + (p[2][r] + p[3][r]);
    }

#pragma unroll
    for (int r = 0; r < 4; ++r) {
      int qr = lg * 4 + r;
#pragma unroll
      for (int j = 0; j < 4; ++j) {
        int ch = (2 * j + (lr >> 3)) ^ (qr & 7);
        lp[w][qr * 64 + ch * 8 + (lr & 7)] = (bf16)p[j][r];
      }
    }
    bf16x8 pa[2];
#pragma unroll
    for (int kf = 0; kf < 2; ++kf)
      pa[kf] = *(const bf16x8*)&lp[w][lr * 64 + (((4 * kf + lg) ^ (lr & 7)) * 8)];

#pragma unroll
    for (int ni = 0; ni < 4; ++ni)
#pragma unroll
      for (int kf = 0; kf < 2; ++kf) {
        int d = ni * 16 + lr;
        bf16x8 vf = *(const bf16x8*)&lv[d * 64 + (((4 * kf + lg) ^ (d & 7)) * 8)];
        o[ni] = __builtin_amdgcn_mfma_f32_16x16x32_bf16(pa[kf], vf, o[ni], 0, 0, 0);
      }
    __syncthreads();
  }

#pragma unroll
  for (int r = 0; r < 4; ++r) {
#pragma unroll
    for (int off = 1; off < 16; off <<= 1) lo[r] += __shfl_xor(lo[r], off);
    lo[r] = 1.f / lo[r];
  }
#pragma unroll
  for (int ni = 0; ni < 4; ++ni)
#pragma unroll
    for (int r = 0; r < 4; ++r) {
      int tq = qw + lg * 4 + r;
      y[(size_t)(b * 2048 + tq) * 1024 + h * 64 + ni * 16 + lr] = (bf16)(o[ni][r] * lo[r]);
    }
}

extern "C" void kernel_launch(void* const* d_in, const int* in_sizes, int n_in,
                              void* d_out, int out_size, void* d_ws, size_t ws_size,
                              hipStream_t stream) {
  (void)in_sizes; (void)n_in; (void)out_size; (void)ws_size;
  const float* x      = (const float*)d_in[0];
  const float* ln1w   = (const float*)d_in[1];
  const float* ln1b   = (const float*)d_in[2];
  const float* ln2w   = (const float*)d_in[3];
  const float* ln2b   = (const float*)d_in[4];
  const float* w_attn = (const float*)d_in[5];
  const float* b_attn = (const float*)d_in[6];
  const float* w_proj = (const float*)d_in[7];
  const float* b_proj = (const float*)d_in[8];
  const float* w_fc   = (const float*)d_in[9];
  const float* b_fc   = (const float*)d_in[10];
  const float* w_fc2  = (const float*)d_in[11];
  const float* b_fc2  = (const float*)d_in[12];
  float* out = (float*)d_out;

  // workspace layout: h | [qkv | y] == m | x1 (vt overlays x1) | weightsT
  char* p = (char*)d_ws;
  bf16*  h     = (bf16*)p;  p += (size_t)8192 * 1024 * 2;
  bf16*  qkv   = (bf16*)p;
  bf16*  mbuf  = (bf16*)p;  p += (size_t)8192 * 3072 * 2;   // m overlays qkv+y
  bf16*  ybuf  = (bf16*)p;  p += (size_t)8192 * 1024 * 2;
  float* x1    = (float*)p; p += (size_t)8192 * 1024 * 4;
  bf16*  wqkvT = (bf16*)p;  p += (size_t)3072 * 1024 * 2;
  bf16*  wprojT= (bf16*)p;  p += (size_t)1024 * 1024 * 2;
  bf16*  wfcT  = (bf16*)p;  p += (size_t)4096 * 1024 * 2;
  bf16*  wfc2T = (bf16*)p;  p += (size_t)1024 * 4096 * 2;
  bf16*  vt    = (bf16*)x1;   // dead until proj-GEMM writes x1 (after attn)

  transpose_cast<<<dim3(1024 / 32, 3072 / 32), 256, 0, stream>>>(w_attn, wqkvT, 1024, 3072);
  transpose_cast<<<dim3(1024 / 32, 1024 / 32), 256, 0, stream>>>(w_proj, wprojT, 1024, 1024);
  transpose_cast<<<dim3(1024 / 32, 4096 / 32), 256, 0, stream>>>(w_fc,   wfcT,  1024, 4096);
  transpose_cast<<<dim3(4096 / 32, 1024 / 32), 256, 0, stream>>>(w_fc2,  wfc2T, 4096, 1024);

  ln_bf16<<<8192, 256, 0, stream>>>(x, ln1w, ln1b, h);
  gemm3<0><<<768, 512, 0, stream>>>(h, wqkvT, b_attn, nullptr, qkv, 8192, 3072, 1024);
  vtrans<<<dim3(64, 32), 256, 0, stream>>>(qkv, vt);
  attn_flash<<<2048, 256, 0, stream>>>(qkv, vt, ybuf);
  gemm3<1><<<256, 512, 0, stream>>>(ybuf, wprojT, b_proj, x, x1, 8192, 1024, 1024);
  ln_bf16<<<8192, 256, 0, stream>>>(x1, ln2w, ln2b, h);
  gemm3<2><<<1024, 512, 0, stream>>>(h, wfcT, b_fc, nullptr, mbuf, 8192, 4096, 1024);
  gemm3<1><<<256, 512, 0, stream>>>(mbuf, wfc2T, b_fc2, x1, out, 8192, 1024, 4096);
}